// Round 1
// 224.841 us; speedup vs baseline: 1.0159x; 1.0159x over previous
//
#include <hip/hip_runtime.h>
#include <math.h>

// Problem constants: token shape (b=16, c=16, n=25, h=16, w=128)
#define SB 819200   // batch stride = c*n*h*w
#define SC 51200    // c stride    = n*h*w
#define SN 2048     // n stride    = h*w
#define CH 256      // c*h  (t dim)
#define NW 3200     // n*w  (k dim of gemm1, s dim of gemm2)
#define NPARTS 10
#define PARTLEN 320         // 3200 / 10 = 5 chunks of 64
#define NCHUNK 5
#define SPART 1048576       // 16*256*256 floats per split-K partial
#define G1BLOCKS 480        // 3 tiles * 10 parts * 16 b

typedef __bf16 bf16x8 __attribute__((ext_vector_type(8)));
typedef __bf16 bf16x4 __attribute__((ext_vector_type(4)));
typedef __bf16 bf16x2 __attribute__((ext_vector_type(2)));
typedef float  f32x4  __attribute__((ext_vector_type(4)));

__device__ __forceinline__ bf16x8 cvt8(float4 a, float4 b) {
    bf16x8 r;
    r[0] = (__bf16)a.x; r[1] = (__bf16)a.y; r[2] = (__bf16)a.z; r[3] = (__bf16)a.w;
    r[4] = (__bf16)b.x; r[5] = (__bf16)b.y; r[6] = (__bf16)b.z; r[7] = (__bf16)b.w;
    return r;
}

__device__ __forceinline__ float dot4(float4 a) {
    return a.x * a.x + a.y * a.y + a.z * a.z + a.w * a.w;
}

// ---------------------------------------------------------------------------
// Kernel 1: split-K bf16-MFMA score GEMM with FUSED row sum-of-squares.
// Spart[p][b][t][r] = sum_{k in part p} Q[t][k]*K[r][k], fp32,
// 128x128 tile, 4 waves of 64x64 (4x4 C-tiles of 16x16x32), causal 3-tile.
// 480 blocks (2/CU sustained); next chunk's global loads are issued BEFORE
// the MFMA phase so HBM latency hides under compute (prev: loads idled).
// Norms: each tile uniquely owns one 128-row panel (tile0: q+k rows 0..127,
// tile1: q rows 128..255, tile2: k rows 128..255); per-part sumsq partials
// written race-free to nq2p/nk2p, finalized in softmax. This deletes the
// old 1024-block norm pass (~104 MB of duplicate HBM reads).
// ---------------------------------------------------------------------------
__global__ __launch_bounds__(256, 2) void gemm1_kernel(const float* __restrict__ q,
                                                       const float* __restrict__ k,
                                                       float* __restrict__ Sp,
                                                       float* __restrict__ nq2p,
                                                       float* __restrict__ nk2p) {
    __shared__ alignas(16) __bf16 As[128 * 72];
    __shared__ alignas(16) __bf16 Bs[128 * 72];

    const int tid = threadIdx.x;
    const int lane = tid & 63;
    const int wave = tid >> 6;

    const int bx = blockIdx.x;
    const int tile = bx % 3;               // 0:(0,0) 1:(1,0) 2:(1,1)
    const int part = (bx / 3) % NPARTS;
    const int b = bx / (3 * NPARTS);
    const int tm = (tile + 1) >> 1;
    const int tn = tile >> 1;

    const int wm = wave >> 1;              // wave m-half (64)
    const int wn = wave & 1;               // wave n-half (64)

    // staging coords: thread covers row = tid>>1, 32 floats at col (tid&1)*32
    const int srow = tid >> 1;
    const int scol = (tid & 1) * 32;
    const int ta = tm * 128 + srow;
    const int rb = tn * 128 + srow;
    const float* qrow = q + (size_t)b * SB + (size_t)(ta >> 4) * SC + (size_t)(ta & 15) * 128;
    const float* krow = k + (size_t)b * SB + (size_t)(rb >> 4) * SC + (size_t)(rb & 15) * 128;

    const bool doQ = (tile != 2);          // this block owns q-rows' sumsq
    const bool doK = (tile != 1);          // this block owns k-rows' sumsq

    f32x4 acc[4][4] = {};
    bool live[4][4];
#pragma unroll
    for (int mi = 0; mi < 4; mi++)
#pragma unroll
        for (int ni = 0; ni < 4; ni++)
            live[mi][ni] = (tn * 128 + wn * 64 + ni * 16) <= (tm * 128 + wm * 64 + mi * 16);

    float sqa = 0.f, sqb = 0.f;
    float4 av[8], bv[8];

    // ---- prologue: stage chunk 0
    {
        const int kg = part * PARTLEN;
        const size_t koff = (size_t)(kg >> 7) * SN + (kg & 127) + scol;
#pragma unroll
        for (int j = 0; j < 8; j++) {
            av[j] = *(const float4*)(qrow + koff + j * 4);
            bv[j] = *(const float4*)(krow + koff + j * 4);
        }
#pragma unroll
        for (int j = 0; j < 4; j++) {
            *(bf16x8*)&As[srow * 72 + scol + j * 8] = cvt8(av[2 * j], av[2 * j + 1]);
            *(bf16x8*)&Bs[srow * 72 + scol + j * 8] = cvt8(bv[2 * j], bv[2 * j + 1]);
        }
        if (doQ) {
#pragma unroll
            for (int j = 0; j < 8; j++) sqa += dot4(av[j]);
        }
        if (doK) {
#pragma unroll
            for (int j = 0; j < 8; j++) sqb += dot4(bv[j]);
        }
    }
    __syncthreads();

    for (int ch = 0; ch < NCHUNK; ch++) {
        // issue next chunk's loads NOW; they fly under the MFMA phase
        if (ch < NCHUNK - 1) {
            const int kg = part * PARTLEN + (ch + 1) * 64;
            const size_t koff = (size_t)(kg >> 7) * SN + (kg & 127) + scol;
#pragma unroll
            for (int j = 0; j < 8; j++) {
                av[j] = *(const float4*)(qrow + koff + j * 4);
                bv[j] = *(const float4*)(krow + koff + j * 4);
            }
        }
        // MFMA phase on current LDS contents
#pragma unroll
        for (int ks = 0; ks < 2; ks++) {
            const int ko = ks * 32 + (lane >> 4) * 8;
            bf16x8 af[4], bf[4];
#pragma unroll
            for (int mi = 0; mi < 4; mi++)
                af[mi] = *(const bf16x8*)&As[(wm * 64 + mi * 16 + (lane & 15)) * 72 + ko];
#pragma unroll
            for (int ni = 0; ni < 4; ni++)
                bf[ni] = *(const bf16x8*)&Bs[(wn * 64 + ni * 16 + (lane & 15)) * 72 + ko];
#pragma unroll
            for (int mi = 0; mi < 4; mi++)
#pragma unroll
                for (int ni = 0; ni < 4; ni++)
                    if (live[mi][ni])
                        acc[mi][ni] = __builtin_amdgcn_mfma_f32_16x16x32_bf16(
                            af[mi], bf[ni], acc[mi][ni], 0, 0, 0);
        }
        if (ch < NCHUNK - 1) {
            __syncthreads();   // all waves done reading current LDS
#pragma unroll
            for (int j = 0; j < 4; j++) {
                *(bf16x8*)&As[srow * 72 + scol + j * 8] = cvt8(av[2 * j], av[2 * j + 1]);
                *(bf16x8*)&Bs[srow * 72 + scol + j * 8] = cvt8(bv[2 * j], bv[2 * j + 1]);
            }
            if (doQ) {
#pragma unroll
                for (int j = 0; j < 8; j++) sqa += dot4(av[j]);
            }
            if (doK) {
#pragma unroll
                for (int j = 0; j < 8; j++) sqb += dot4(bv[j]);
            }
            __syncthreads();
        }
    }

    // ---- Spart epilogue
    float* o = Sp + (size_t)part * SPART + (size_t)b * 65536;
#pragma unroll
    for (int mi = 0; mi < 4; mi++)
#pragma unroll
        for (int ni = 0; ni < 4; ni++) {
            if (!live[mi][ni]) continue;
            const int r = tn * 128 + wn * 64 + ni * 16 + (lane & 15);
#pragma unroll
            for (int j = 0; j < 4; j++) {
                const int t = tm * 128 + wm * 64 + mi * 16 + (lane >> 4) * 4 + j;
                o[(size_t)t * 256 + r] = acc[mi][ni][j];
            }
        }

    // ---- sumsq epilogue: lanes (2i, 2i+1) hold the two col-halves of row srow
    sqa += __shfl_xor(sqa, 1, 64);
    sqb += __shfl_xor(sqb, 1, 64);
    if (!(lane & 1)) {
        if (doQ) nq2p[part * 4096 + b * 256 + ta] = sqa;
        if (doK) nk2p[part * 4096 + b * 256 + rb] = sqb;
    }
}

// ---------------------------------------------------------------------------
// Kernel 2: sum split-K partials, finalize inverse norms from sumsq partials,
// causal mask, softmax, write P as bf16. One wave per (b,t) row.
// ---------------------------------------------------------------------------
__global__ __launch_bounds__(256) void softmax_kernel(const float* __restrict__ Sp,
                                                      const float* __restrict__ nq2p,
                                                      const float* __restrict__ nk2p,
                                                      __bf16* __restrict__ P) {
    const int wave = threadIdx.x >> 6;
    const int lane = threadIdx.x & 63;
    const int t = blockIdx.x * 4 + wave;
    const int b = blockIdx.y;
    const size_t rowbase = ((size_t)b * 256 + t) * 256;
    const int r0 = lane * 4;

    float4 s4 = {0.f, 0.f, 0.f, 0.f};
#pragma unroll
    for (int p = 0; p < NPARTS; p++) {
        const float4 x = *(const float4*)(Sp + (size_t)p * SPART + rowbase + r0);
        s4.x += x.x; s4.y += x.y; s4.z += x.z; s4.w += x.w;
    }
    float sq = 0.f;
#pragma unroll
    for (int p = 0; p < NPARTS; p++) sq += nq2p[p * 4096 + b * 256 + t];
    float4 sk = {0.f, 0.f, 0.f, 0.f};
#pragma unroll
    for (int p = 0; p < NPARTS; p++) {
        const float4 x = *(const float4*)(nk2p + p * 4096 + b * 256 + r0);
        sk.x += x.x; sk.y += x.y; sk.z += x.z; sk.w += x.w;
    }
    const float qn = 1.0f / fmaxf(sqrtf(sq), 1e-12f);
    float4 kn;
    kn.x = 1.0f / fmaxf(sqrtf(sk.x), 1e-12f);
    kn.y = 1.0f / fmaxf(sqrtf(sk.y), 1e-12f);
    kn.z = 1.0f / fmaxf(sqrtf(sk.z), 1e-12f);
    kn.w = 1.0f / fmaxf(sqrtf(sk.w), 1e-12f);

    float val[4] = {s4.x * qn * kn.x, s4.y * qn * kn.y,
                    s4.z * qn * kn.z, s4.w * qn * kn.w};
    float m = -1e30f;
#pragma unroll
    for (int j = 0; j < 4; j++) {
        if (r0 + j > t) val[j] = -1e30f;
        m = fmaxf(m, val[j]);
    }
#pragma unroll
    for (int off = 32; off; off >>= 1) m = fmaxf(m, __shfl_xor(m, off, 64));

    float e[4], sum = 0.f;
#pragma unroll
    for (int j = 0; j < 4; j++) {
        e[j] = (r0 + j <= t) ? expf(val[j] - m) : 0.f;
        sum += e[j];
    }
#pragma unroll
    for (int off = 32; off; off >>= 1) sum += __shfl_xor(sum, off, 64);

    const float inv = 1.0f / sum;
    bf16x4 o;
    o[0] = (__bf16)(e[0] * inv);
    o[1] = (__bf16)(e[1] * inv);
    o[2] = (__bf16)(e[2] * inv);
    o[3] = (__bf16)(e[3] * inv);
    *(bf16x4*)(P + rowbase + r0) = o;
}

// ---------------------------------------------------------------------------
// Kernel 3: O[t][s] = sum_r P[t][r]*V[r][s] + V[t][s], bf16 MFMA.
// Block = 128 t x 64 s (half of one n), K = 256 r in 4 chunks of 64.
// P A-fragments load DIRECTLY from global (natural [t][r] layout == A-frag
// layout; P is 2 MB, L2-hot). Only V goes through LDS (transposed, paired-row
// b32 stores, XOR swizzle). grid (50 nw, 2 t-tiles, 16 b) = 1600 blocks.
// ---------------------------------------------------------------------------
__global__ __launch_bounds__(256, 4) void gemm2_kernel(const __bf16* __restrict__ P,
                                                       const float* __restrict__ v,
                                                       float* __restrict__ out) {
    __shared__ alignas(16) char smem[9216];
    __bf16* Vs = (__bf16*)smem;     // [64 s][72 r-stride]  (9216 B)
    float* Es = (float*)smem;       // [32][68] epilogue reuse (8704 B)

    const int tid = threadIdx.x;
    const int b = blockIdx.z;
    const int tt = blockIdx.y;      // 0..1 (t 128-half)
    const int nw = blockIdx.x;      // 0..49
    const int n = nw >> 1;
    const int whalf = nw & 1;

    const int lane = tid & 63;
    const int wave = tid >> 6;
    const int wm = wave >> 1;       // t 64-half within 128-tile
    const int wn = wave & 1;        // s 32-half within 64-tile
    const int l15 = lane & 15;
    const int quad = lane >> 4;

    // V staging coords: thread covers s-group vu*8..+7, row pair 2rp, 2rp+1
    const int vu = tid & 7;
    const int rp = tid >> 3;        // 0..31
    const float* vbase = v + (size_t)b * SB + (size_t)n * SN + whalf * 64;

    // P A-frag base: row = tt*128 + wm*64 + mi*16 + l15, col = kc*64+ks*32+quad*8
    const __bf16* Pbase = P + ((size_t)b * 256 + tt * 128 + wm * 64 + l15) * 256 + quad * 8;

    f32x4 acc[4][2] = {};

    for (int kc = 0; kc < 4; kc++) {
        // A fragments direct from global (issued early, L2-hot)
        bf16x8 af[4][2];
#pragma unroll
        for (int mi = 0; mi < 4; mi++)
#pragma unroll
            for (int ks = 0; ks < 2; ks++)
                af[mi][ks] = *(const bf16x8*)(Pbase + (size_t)mi * 16 * 256 + kc * 64 + ks * 32);

        // V loads: rows 2rp, 2rp+1 of this r-chunk, 8 floats each
        float vr0[8], vr1[8];
        {
            const int r0 = kc * 64 + 2 * rp;
            const int r1 = r0 + 1;
            const float* row0 = vbase + (size_t)(r0 >> 4) * SC + (size_t)(r0 & 15) * 128;
            const float* row1 = vbase + (size_t)(r1 >> 4) * SC + (size_t)(r1 & 15) * 128;
            *(float4*)&vr0[0] = *(const float4*)(row0 + vu * 8);
            *(float4*)&vr0[4] = *(const float4*)(row0 + vu * 8 + 4);
            *(float4*)&vr1[0] = *(const float4*)(row1 + vu * 8);
            *(float4*)&vr1[4] = *(const float4*)(row1 + vu * 8 + 4);
        }
        __syncthreads();   // prior Vs reads (or Es init) done
        {
            const int rl0 = 2 * rp;
#pragma unroll
            for (int sj = 0; sj < 8; sj++) {
                const int s = vu * 8 + sj;
                bf16x2 pr;
                pr[0] = (__bf16)vr0[sj];
                pr[1] = (__bf16)vr1[sj];
                *(bf16x2*)&Vs[s * 72 + (rl0 ^ (s & 0x38))] = pr;
            }
        }
        __syncthreads();
#pragma unroll
        for (int ks = 0; ks < 2; ks++) {
            bf16x8 bfr[2];
#pragma unroll
            for (int ni = 0; ni < 2; ni++) {
                const int s = wn * 32 + ni * 16 + l15;
                bfr[ni] = *(const bf16x8*)&Vs[s * 72 + ((ks * 32 + quad * 8) ^ (s & 0x38))];
            }
#pragma unroll
            for (int mi = 0; mi < 4; mi++)
#pragma unroll
                for (int ni = 0; ni < 2; ni++)
                    acc[mi][ni] = __builtin_amdgcn_mfma_f32_16x16x32_bf16(
                        af[mi][ks], bfr[ni], acc[mi][ni], 0, 0, 0);
        }
    }

    // ---- epilogue: 4 passes of 32 t-rows through Es[32][68], coalesced out
    for (int p = 0; p < 4; p++) {
        __syncthreads();   // prior Vs/Es reads done
        if (wm == (p >> 1)) {
            const int mibase = (p & 1) * 2;
#pragma unroll
            for (int mm = 0; mm < 2; mm++)
#pragma unroll
                for (int ni = 0; ni < 2; ni++) {
                    const f32x4 a = acc[mibase + mm][ni];
                    const int wcol = wn * 32 + ni * 16 + l15;
#pragma unroll
                    for (int j = 0; j < 4; j++)
                        Es[(mm * 16 + quad * 4 + j) * 68 + wcol] = a[j];
                }
        }
        __syncthreads();
#pragma unroll
        for (int it = 0; it < 2; it++) {
            const int tl = it * 16 + (tid >> 4);      // 0..31
            const int w4 = (tid & 15) * 4;            // 0..60
            const int t = tt * 128 + p * 32 + tl;
            const size_t a = (size_t)b * SB + (size_t)(t >> 4) * SC + (size_t)n * SN +
                             (size_t)(t & 15) * 128 + whalf * 64 + w4;
            float4 r4 = *(const float4*)&Es[tl * 68 + w4];
            const float4 buf = *(const float4*)(v + a);
            r4.x += buf.x; r4.y += buf.y; r4.z += buf.z; r4.w += buf.w;
            *(float4*)(out + a) = r4;
        }
    }
}

// ---------------------------------------------------------------------------
extern "C" void kernel_launch(void* const* d_in, const int* in_sizes, int n_in,
                              void* d_out, int out_size, void* d_ws, size_t ws_size,
                              hipStream_t stream) {
    const float* q = (const float*)d_in[0];
    const float* k = (const float*)d_in[1];
    const float* v = (const float*)d_in[2];
    float* out = (float*)d_out;

    float* ws = (float*)d_ws;
    float* nq2p = ws;                          // 10*4096 floats (sumsq partials)
    float* nk2p = ws + 40960;                  // 10*4096 floats
    __bf16* P = (__bf16*)(ws + 81920);         // 16*256*256 bf16 = 2 MB

    // d_out doubles as split-K scratch (10 * 4 MB = 42 MB <= 52 MB out),
    // fully overwritten by gemm2 afterwards.
    float* Spart = out;

    gemm1_kernel<<<dim3(G1BLOCKS), dim3(256), 0, stream>>>(q, k, Spart, nq2p, nk2p);
    softmax_kernel<<<dim3(64, 16), dim3(256), 0, stream>>>(Spart, nq2p, nk2p, P);
    gemm2_kernel<<<dim3(50, 2, 16), dim3(256), 0, stream>>>(P, v, out);
}